// Round 10
// baseline (37.683 us; speedup 1.0000x reference)
//
#include <hip/hip_runtime.h>
#include <math.h>

// Diversity8: loss = mean_b( 0.3 * 0.5 * sum_{m!=n} corr(p_m[b], p_n[b]) )
// corr is scale/shift-invariant -> softmax 1/S cancels. With
// u_m[c] = exp(x_m[c]/T) - 1:  cov_mn = <u_m,u_n> - t_m t_n / C,
// corr_mn = cov_mn / sqrt(cov_mm cov_nn).
// R10: TWO waves per sample (8192 waves = 8/SIMD supply vs R9's 4), each wave
// owns 500 classes: 16 upfront loads in 2 batches (half R9's serial latency
// chain). 44 lane-local partials (36 Gram + 8 sums), DPP reduction on the
// VALU pipe (cheap fixed cost, unlike R8's shfl/LDS-pipe tax), halves
// combined through 384B LDS + one barrier; epilogue redundant on all lanes.

constexpr int NC    = 1000;
constexpr int NM    = 8;
constexpr int NPAIR = NM * (NM + 1) / 2;   // 36 (m<=n)
constexpr float KEXP = 0.072134752044448169f;  // log2(e)/20: exp(x/20)=exp2(x*KEXP)
constexpr float INVC = 1.0f / (float)NC;

// ---- full-wave (64-lane) sum on the VALU pipe; result broadcast to all lanes
__device__ __forceinline__ float dppSumBcast(float v) {
    // row_shr:1,2,4,8 -> lane 15/31/47/63 hold their 16-lane row sums
    v += __int_as_float(__builtin_amdgcn_update_dpp(
            0, __float_as_int(v), 0x111, 0xf, 0xf, false));
    v += __int_as_float(__builtin_amdgcn_update_dpp(
            0, __float_as_int(v), 0x112, 0xf, 0xf, false));
    v += __int_as_float(__builtin_amdgcn_update_dpp(
            0, __float_as_int(v), 0x114, 0xf, 0xf, false));
    v += __int_as_float(__builtin_amdgcn_update_dpp(
            0, __float_as_int(v), 0x118, 0xf, 0xf, false));
    // row_bcast:15 -> lane31 += lane15, lane63 += lane47
    v += __int_as_float(__builtin_amdgcn_update_dpp(
            0, __float_as_int(v), 0x142, 0xf, 0xf, false));
    // row_bcast:31 -> lane63 += lane31  (lane 63 = full sum)
    v += __int_as_float(__builtin_amdgcn_update_dpp(
            0, __float_as_int(v), 0x143, 0xf, 0xf, false));
    return __int_as_float(__builtin_amdgcn_readlane(__float_as_int(v), 63));
}

__device__ __forceinline__ double waveSumD(double v) {
#pragma unroll
    for (int o = 32; o > 0; o >>= 1) v += __shfl_xor(v, o, 64);
    return v;
}
// triangular index for m<=n, NM=8; constant-folds under full unroll
__device__ __forceinline__ constexpr int tidx(int m, int n) {
    return m * (2 * NM - m + 1) / 2 + (n - m);
}

__global__ __launch_bounds__(128) void div8_main(
    const float* __restrict__ in0, const float* __restrict__ in1,
    const float* __restrict__ in2, const float* __restrict__ in3,
    const float* __restrict__ in4, const float* __restrict__ in5,
    const float* __restrict__ in6, const float* __restrict__ in7,
    float* __restrict__ part)
{
    const int wid  = threadIdx.x >> 6;   // 0..1: class-half of this sample
    const int lane = threadIdx.x & 63;
    const int b    = blockIdx.x;         // one block per sample

    const float4* p4[NM] = {
        reinterpret_cast<const float4*>(in0 + (size_t)b * NC),
        reinterpret_cast<const float4*>(in1 + (size_t)b * NC),
        reinterpret_cast<const float4*>(in2 + (size_t)b * NC),
        reinterpret_cast<const float4*>(in3 + (size_t)b * NC),
        reinterpret_cast<const float4*>(in4 + (size_t)b * NC),
        reinterpret_cast<const float4*>(in5 + (size_t)b * NC),
        reinterpret_cast<const float4*>(in6 + (size_t)b * NC),
        reinterpret_cast<const float4*>(in7 + (size_t)b * NC) };

    // wave wid owns float4 indices [125*wid, 125*wid+125):
    //   batch A: base+lane (all 64 valid), batch B: base+64+lane (lane<61)
    const int   base = 125 * wid;
    const bool  v1   = lane < 61;
    const int   i0   = base + lane;
    const int   i1   = v1 ? (base + 64 + lane) : base;  // clamped, masked to 0
    const float m1   = v1 ? 1.f : 0.f;

    // ---- 16 loads upfront (2 batches) ----
    float4 A[NM], Bv[NM];
#pragma unroll
    for (int m = 0; m < NM; ++m) A[m]  = p4[m][i0];
#pragma unroll
    for (int m = 0; m < NM; ++m) Bv[m] = p4[m][i1];

    // ---- u = (exp2(v*K) - 1) * mask ; fma folds mask & subtract ----
#pragma unroll
    for (int m = 0; m < NM; ++m) {
        A[m].x  = exp2f(A[m].x * KEXP) - 1.f;
        A[m].y  = exp2f(A[m].y * KEXP) - 1.f;
        A[m].z  = exp2f(A[m].z * KEXP) - 1.f;
        A[m].w  = exp2f(A[m].w * KEXP) - 1.f;
        Bv[m].x = fmaf(exp2f(Bv[m].x * KEXP), m1, -m1);
        Bv[m].y = fmaf(exp2f(Bv[m].y * KEXP), m1, -m1);
        Bv[m].z = fmaf(exp2f(Bv[m].z * KEXP), m1, -m1);
        Bv[m].w = fmaf(exp2f(Bv[m].w * KEXP), m1, -m1);
    }

    // ---- lane-local Gram: 36 pair-products + 8 sums over 8 class slots ----
    float D[NPAIR], t[NM];
#pragma unroll
    for (int k = 0; k < NPAIR; ++k) D[k] = 0.f;
#pragma unroll
    for (int m = 0; m < NM; ++m) t[m] = 0.f;

#pragma unroll
    for (int s = 0; s < 8; ++s) {
        float us[NM];
#pragma unroll
        for (int m = 0; m < NM; ++m) {
            us[m] = (s == 0) ? A[m].x  : (s == 1) ? A[m].y
                  : (s == 2) ? A[m].z  : (s == 3) ? A[m].w
                  : (s == 4) ? Bv[m].x : (s == 5) ? Bv[m].y
                  : (s == 6) ? Bv[m].z : Bv[m].w;
        }
#pragma unroll
        for (int m = 0; m < NM; ++m) {
            t[m] += us[m];
#pragma unroll
            for (int n = m; n < NM; ++n)
                D[tidx(m, n)] = fmaf(us[m], us[n], D[tidx(m, n)]);
        }
    }

    // ---- 44 independent DPP reductions (VALU pipe; results broadcast) ----
#pragma unroll
    for (int k = 0; k < NPAIR; ++k) D[k] = dppSumBcast(D[k]);
#pragma unroll
    for (int m = 0; m < NM; ++m) t[m] = dppSumBcast(t[m]);

    // ---- combine the two class-halves through LDS (384B), one barrier ----
    __shared__ float comb[2][48];
    if (lane == 0) {
#pragma unroll
        for (int k4 = 0; k4 < 9; ++k4)
            *reinterpret_cast<float4*>(&comb[wid][k4 * 4]) =
                make_float4(D[k4 * 4], D[k4 * 4 + 1], D[k4 * 4 + 2], D[k4 * 4 + 3]);
#pragma unroll
        for (int m4 = 0; m4 < 2; ++m4)
            *reinterpret_cast<float4*>(&comb[wid][36 + m4 * 4]) =
                make_float4(t[m4 * 4], t[m4 * 4 + 1], t[m4 * 4 + 2], t[m4 * 4 + 3]);
    }
    __syncthreads();

    // ---- epilogue, redundant on all 128 threads (broadcast LDS reads) ----
    float Gd[NPAIR], Gt[NM];
#pragma unroll
    for (int k = 0; k < NPAIR; ++k) Gd[k] = comb[0][k] + comb[1][k];
#pragma unroll
    for (int m = 0; m < NM; ++m) Gt[m] = comb[0][36 + m] + comb[1][36 + m];

    float rm[NM];
#pragma unroll
    for (int m = 0; m < NM; ++m) {
        // cov_mm: D_mm ~ 2.5, correction ~ 0.0016 -> no cancellation
        float q = fmaf(-Gt[m] * INVC, Gt[m], Gd[tidx(m, m)]);
        rm[m] = 1.0f / sqrtf(q);
    }
    double cr = 0.0;
#pragma unroll
    for (int m = 0; m < NM; ++m)
#pragma unroll
        for (int n = m + 1; n < NM; ++n) {
            float cov = fmaf(-Gt[m] * INVC, Gt[n], Gd[tidx(m, n)]);
            cr += (double)(cov * rm[m] * rm[n]);
        }
    if (threadIdx.x == 0) part[b] = (float)(2.0 * cr);  // = sum_{m!=n} corr_mn
}

__global__ __launch_bounds__(256) void div8_final(
    const float* __restrict__ part, float* __restrict__ out, int B)
{
    const int t = threadIdx.x;
    double acc = 0.0;
    for (int i = t; i < B; i += 256) acc += (double)part[i];  // fixed order: deterministic
    acc = waveSumD(acc);
    __shared__ double redd[4];
    if ((t & 63) == 0) redd[t >> 6] = acc;
    __syncthreads();
    if (t == 0) {
        double tot = (redd[0] + redd[1]) + (redd[2] + redd[3]);
        // loss = mean( 0.3 * 0.5 * cross_b )
        out[0] = (float)(tot * (0.5 * 0.3 / (double)B));
    }
}

extern "C" void kernel_launch(void* const* d_in, const int* in_sizes, int n_in,
                              void* d_out, int out_size, void* d_ws, size_t ws_size,
                              hipStream_t stream)
{
    const float* a0 = (const float*)d_in[0];
    const float* a1 = (const float*)d_in[1];
    const float* a2 = (const float*)d_in[2];
    const float* a3 = (const float*)d_in[3];
    const float* a4 = (const float*)d_in[4];
    const float* a5 = (const float*)d_in[5];
    const float* a6 = (const float*)d_in[6];
    const float* a7 = (const float*)d_in[7];
    const int B = in_sizes[0] / NC;   // 4096

    float* part = (float*)d_ws;       // B floats of scratch

    div8_main<<<B, 128, 0, stream>>>(a0, a1, a2, a3, a4, a5, a6, a7, part);
    div8_final<<<1, 256, 0, stream>>>(part, (float*)d_out, B);
}